// Round 5
// baseline (1063.424 us; speedup 1.0000x reference)
//
#include <hip/hip_runtime.h>
#include <hip/hip_bf16.h>

// KroneckerMixer: B=64, N=1024, K=64, BASIS=8, T=0.2, 20 sinkhorn iters.
// R11 pipeline (bf16 path, ws >= 40.25 MB):
//   k_front : fused, grid 256 x 1024 (1 block/CU, all co-resident).
//     Blocks 0..15 = A-sinkhorn u/v solver (R9-verbatim): E in registers,
//       lane-stride-64 layout, flagless per-iteration exchange buffers
//       (value-as-flag, partials > 0). These blocks do NO W work.
//     Blocks 16..255 = W-path, REDESIGNED: one n per WAVE, fully in-register.
//       Lane c holds E[:,c] (64 VGPR). Row sums via 63-op ds_bpermute
//       butterfly (register reduce-transpose, no LDS tiles, no barriers).
//       u broadcast through a per-wave 256B LDS line (same-wave in-order
//       DS pipe). Col pass is 64 in-lane FMAs (v lane-local, zero comm).
//       Matmul in-wave: W = e*u in regs, lane-uniform x loads (broadcast),
//       v-scale folded AFTER accumulation (v factors out per out-column).
//       Waves 0..3 active (1 per SIMD); blocks 16..31 run 2 rounds (8 n's),
//       blocks 32..255 one round (4 n's): 16*8 + 224*4 = 1024.
//   k_xt    : transpose + v-scale + hi/lo split XL -> XTh/XTl bf16 [c][n].
//   k_gemm3 : out[m][c] = u_m*(Eh*XTh + El*XTh + Eh*XTl) via mfma 16x16x32.
// Fallback (small ws): fp32 k_gemm reading E0 with u/v folded.

#define N_DIM 1024
#define INV_T 5.0f
#define NBAR 16  // A-sinkhorn blocks

typedef __attribute__((ext_vector_type(8))) short short8;
typedef __attribute__((ext_vector_type(4))) float float4v;

// ---------------- wave64 sum reduction via DPP (VALU pipe) -------------------
// Result valid in lane 63.
__device__ __forceinline__ float wave_red_sum(float x) {
#define DPP_ADD(C)                                                            \
  {                                                                           \
    int _y = __builtin_amdgcn_update_dpp(0, __float_as_int(x), (C), 0xf, 0xf, \
                                         true);                               \
    x += __int_as_float(_y);                                                  \
  }
  DPP_ADD(0x111);
  DPP_ADD(0x112);
  DPP_ADD(0x114);
  DPP_ADD(0x118);
  DPP_ADD(0x142);
  DPP_ADD(0x143);
#undef DPP_ADD
  return x;
}

// ---------------- kernel 1: fused sinkA(u,v) + wpath -------------------------
// grid 256 x 1024.
__global__ __launch_bounds__(1024) void k_front(
    const float* __restrict__ x, const float* __restrict__ L,
    const float* __restrict__ W1, const float* __restrict__ WV,
    float* __restrict__ E0, __hip_bfloat16* __restrict__ Eh,
    __hip_bfloat16* __restrict__ El, float* __restrict__ P,
    unsigned* __restrict__ ctrl, float* __restrict__ u_g,
    float* __restrict__ v_g, float* __restrict__ XL, int write_bf16) {
  __shared__ __align__(16) float smem[9312];
  const int t = threadIdx.x;
  const int bid = blockIdx.x;
  const int lane = t & 63;
  const int w = t >> 6;  // 0..15
  (void)ctrl;

  if (bid < NBAR) {
    // =================== A-sinkhorn u/v role (E in registers) ===============
    // Layout: e[j][k] = E[r0 + 4w + j][k*64 + lane]  (lane-stride-64 cols)
    float* v_s = smem;              // [1024]
    float* uS = smem + 1024;        // [64]
    float* red = smem + 1024 + 64;  // [8][1028] cross-wave reduce buffer
    const int b = bid;
    const int r0 = b * 64;

    // ---- prologue: e = exp(L/T); emit Eh/El (bf16 hi/lo) or E0 (fp32)
    float e[4][16];
#pragma unroll
    for (int j = 0; j < 4; ++j) {
      const int r = r0 + 4 * w + j;
      const float* Lr = L + (size_t)r * N_DIM + lane;
#pragma unroll
      for (int k = 0; k < 16; ++k) e[j][k] = __expf(Lr[k * 64] * INV_T);
      if (write_bf16) {
        __hip_bfloat16* EhR = Eh + (size_t)r * N_DIM + lane;
        __hip_bfloat16* ElR = El + (size_t)r * N_DIM + lane;
#pragma unroll
        for (int k = 0; k < 16; ++k) {
          __hip_bfloat16 h = __float2bfloat16(e[j][k]);
          EhR[k * 64] = h;
          ElR[k * 64] = __float2bfloat16(e[j][k] - __bfloat162float(h));
        }
      } else {
        float* ER = E0 + (size_t)r * N_DIM + lane;
#pragma unroll
        for (int k = 0; k < 16; ++k) ER[k * 64] = e[j][k];
      }
    }
    v_s[t] = 1.0f;  // iter0 row pass sums raw e (v == 1)
    __syncthreads();

    for (int it = 0; it < 20; ++it) {
      // ---- row pass: u_i = 1/sum_c e[i][c]*v[c]  (conflict-free v reads)
      float vv[16];
#pragma unroll
      for (int k = 0; k < 16; ++k) vv[k] = v_s[k * 64 + lane];
      float u[4];
#pragma unroll
      for (int j = 0; j < 4; ++j) {
        float p = 0.f;
#pragma unroll
        for (int k = 0; k < 16; ++k) p += e[j][k] * vv[k];
        p = wave_red_sum(p);  // lane 63
        u[j] = 1.0f /
               __int_as_float(__builtin_amdgcn_readlane(__float_as_int(p), 63));
      }
      // ---- col partials for this wave's 4 rows (col = k*64+lane)
      float cpl[16];
#pragma unroll
      for (int k = 0; k < 16; ++k)
        cpl[k] = e[0][k] * u[0] + e[1][k] * u[1] + e[2][k] * u[2] +
                 e[3][k] * u[3];
      // ---- cross-wave reduce 16->8 (all accesses lane-consecutive)
      if (w >= 8) {
#pragma unroll
        for (int k = 0; k < 16; ++k)
          red[(w - 8) * 1028 + k * 64 + lane] = cpl[k];
      }
      __syncthreads();
      if (w < 8) {
#pragma unroll
        for (int k = 0; k < 16; ++k) red[w * 1028 + k * 64 + lane] += cpl[k];
      }
      __syncthreads();
      // ---- block col sum (thread t = col t)
      float cp = 0.f;
#pragma unroll
      for (int ww = 0; ww < 8; ++ww) cp += red[ww * 1028 + t];
      // ---- exchange: store to THIS iteration's buffer (value-as-flag)
      float* Pit = P + (size_t)it * (NBAR * N_DIM);
      __hip_atomic_store(&Pit[b * N_DIM + t], cp, __ATOMIC_RELAXED,
                         __HIP_MEMORY_SCOPE_AGENT);
      if (it == 19 && lane == 0) {
#pragma unroll
        for (int j = 0; j < 4; ++j) uS[4 * w + j] = u[j];
      }
      // ---- gather: parallel loads, retry only zeros (partials are > 0)
      unsigned vals[NBAR];
#pragma unroll
      for (int pb = 0; pb < NBAR; ++pb)
        vals[pb] = (pb == b)
                       ? __float_as_uint(cp)
                       : __hip_atomic_load(
                             (const unsigned*)&Pit[pb * N_DIM + t],
                             __ATOMIC_RELAXED, __HIP_MEMORY_SCOPE_AGENT);
      for (;;) {
        unsigned miss = 0u;
#pragma unroll
        for (int pb = 0; pb < NBAR; ++pb) miss |= (vals[pb] == 0u) ? 1u : 0u;
        if (miss == 0u) break;
#pragma unroll
        for (int pb = 0; pb < NBAR; ++pb)
          if (vals[pb] == 0u)
            vals[pb] = __hip_atomic_load(
                (const unsigned*)&Pit[pb * N_DIM + t], __ATOMIC_RELAXED,
                __HIP_MEMORY_SCOPE_AGENT);
      }
      float s2 = 0.f;
#pragma unroll
      for (int pb = 0; pb < NBAR; ++pb) s2 += __uint_as_float(vals[pb]);
      v_s[t] = 1.0f / s2;
      __syncthreads();
    }
    // ---- epilogue: emit u (this block's 64 rows) and v (block 0)
    if (t < 64) u_g[r0 + t] = uS[t];
    if (b == 0) v_g[t] = v_s[t];
    return;  // A blocks do no W work
  }

  // =========== W-path: one n per wave, fully in-register ====================
  if (w >= 4) return;  // waves 0..3 only (one per SIMD); no barriers below
  float* ug = smem + w * 64;  // per-wave 256B u-broadcast line

  int nlist[2];
  int rounds;
  if (bid < 32) {
    rounds = 2;
    nlist[0] = (bid - 16) * 8 + w;
    nlist[1] = (bid - 16) * 8 + 4 + w;
  } else {
    rounds = 1;
    nlist[0] = 128 + (bid - 32) * 4 + w;
    nlist[1] = 0;
  }

  const int pidx = lane << 2;  // bpermute byte index base

  for (int r = 0; r < rounds; ++r) {
    const int n = nlist[r];
    // ---- logits: lane c holds E[:,c]; e[i] = exp(INV_T * sum_k w1 WV[k][i][c])
    float w1[8];
#pragma unroll
    for (int k = 0; k < 8; ++k) w1[k] = W1[n * 8 + k];
    float e[64];
#pragma unroll
    for (int i = 0; i < 64; ++i) {
      float acc = 0.f;
#pragma unroll
      for (int k = 0; k < 8; ++k) acc += w1[k] * WV[k * 4096 + i * 64 + lane];
      e[i] = __expf(acc * INV_T);
    }

    // ---- 20 sinkhorn iterations, in-wave
    float v = 1.0f;
    for (int it = 0; it < 20; ++it) {
      // row sums via register butterfly reduce-transpose:
      // lane l ends with rowsum[l] = sum_c e_c[l]*v_c
      float a[32];
      {
        const bool hi = (lane & 32) != 0;
        const int pj = pidx ^ (32 << 2);
#pragma unroll
        for (int j = 0; j < 32; ++j) {
          float s0 = (hi ? e[j] : e[j + 32]) * v;
          float k0 = (hi ? e[j + 32] : e[j]) * v;
          a[j] = k0 + __int_as_float(__builtin_amdgcn_ds_bpermute(
                          pj, __float_as_int(s0)));
        }
      }
#define BSTAGE(D)                                                          \
  {                                                                        \
    const bool hi = (lane & (D)) != 0;                                     \
    const int pj = pidx ^ ((D) << 2);                                      \
    _Pragma("unroll") for (int j = 0; j < (D); ++j) {                      \
      float s0 = hi ? a[j] : a[j + (D)];                                   \
      float k0 = hi ? a[j + (D)] : a[j];                                   \
      a[j] = k0 + __int_as_float(                                          \
                      __builtin_amdgcn_ds_bpermute(pj, __float_as_int(s0))); \
    }                                                                      \
  }
      BSTAGE(16)
      BSTAGE(8)
      BSTAGE(4)
      BSTAGE(2)
      BSTAGE(1)
#undef BSTAGE
      const float u_l = 1.0f / a[0];
      ug[lane] = u_l;  // same-wave in-order DS pipe: reads below see this
      // col pass: v_c = 1/sum_i e[i][c]*u[i]  (u broadcast, v lane-local)
      float s2 = 0.f;
#pragma unroll
      for (int q = 0; q < 16; ++q) {
        float4 u4 = *(const float4*)&ug[4 * q];
        s2 += e[4 * q] * u4.x + e[4 * q + 1] * u4.y + e[4 * q + 2] * u4.z +
              e[4 * q + 3] * u4.w;
      }
      v = 1.0f / s2;
    }

    // ---- fold u into e:  e[i] <- e[i]*u[i]   (W[i][c] = e[i]*u[i]*v)
#pragma unroll
    for (int q = 0; q < 16; ++q) {
      float4 u4 = *(const float4*)&ug[4 * q];
      e[4 * q] *= u4.x;
      e[4 * q + 1] *= u4.y;
      e[4 * q + 2] *= u4.z;
      e[4 * q + 3] *= u4.w;
    }

    // ---- in-wave matmul: x_local[bb][c] = v * sum_i x[bb][n*64+i]*e[i]
    const float* xn = x + (size_t)n * 64;
    float* xl = XL + (size_t)n * 4096;
#pragma unroll 4
    for (int bb = 0; bb < 64; ++bb) {
      const float* xr = xn + (size_t)bb * 65536;
      float acc = 0.f;
#pragma unroll
      for (int q = 0; q < 16; ++q) {
        float4 xb = *(const float4*)&xr[4 * q];  // lane-uniform -> broadcast
        acc += xb.x * e[4 * q] + xb.y * e[4 * q + 1] + xb.z * e[4 * q + 2] +
               xb.w * e[4 * q + 3];
      }
      xl[bb * 64 + lane] = acc * v;  // coalesced 256B store
    }
  }
}

// ---------------- kernel 2b: transpose + v-scale + hi/lo split ---------------
// XTh/XTl[c][n] = hi/lo bf16 of (v[n] * XL[n][c]).
__global__ __launch_bounds__(256) void k_xt(const float* __restrict__ XL,
                                            const float* __restrict__ v_g,
                                            __hip_bfloat16* __restrict__ XTh,
                                            __hip_bfloat16* __restrict__ XTl) {
  __shared__ float T[64 * 68];
  __shared__ float vsh[64];
  const int t = threadIdx.x;
  const int n0 = blockIdx.x * 64;
  const int c0 = blockIdx.y * 64;
  if (t < 64) vsh[t] = v_g[n0 + t];
  {
    const int r = t >> 4;         // 0..15
    const int c4 = (t & 15) * 4;  // 0..60
#pragma unroll
    for (int p = 0; p < 4; ++p) {
      float4 f =
          *(const float4*)&XL[(size_t)(n0 + r + 16 * p) * 4096 + c0 + c4];
      *(float4*)&T[(r + 16 * p) * 68 + c4] = f;
    }
  }
  __syncthreads();
  const int cl = t >> 2;        // 0..63
  const int nb = (t & 3) * 16;  // 0,16,32,48
  __align__(16) __hip_bfloat16 hbuf[16];
  __align__(16) __hip_bfloat16 lbuf[16];
#pragma unroll
  for (int j = 0; j < 16; ++j) {
    float xv = T[(nb + j) * 68 + cl] * vsh[nb + j];
    __hip_bfloat16 h = __float2bfloat16(xv);
    hbuf[j] = h;
    lbuf[j] = __float2bfloat16(xv - __bfloat162float(h));
  }
  const size_t off = (size_t)(c0 + cl) * 1024 + n0 + nb;
  *(uint4*)&XTh[off] = *(uint4*)&hbuf[0];
  *(uint4*)&XTh[off + 8] = *(uint4*)&hbuf[8];
  *(uint4*)&XTl[off] = *(uint4*)&lbuf[0];
  *(uint4*)&XTl[off + 8] = *(uint4*)&lbuf[8];
}

// ---------------- kernel 3 (bf16): out = u ⊙ (Eh*XTh + El*XTh + Eh*XTl) ------
// D[m=1024][c=4096], 128x128 block tile, 4 waves each 64x64 of 16x16x32 MFMA.
#define LSTR 72  // padded LDS row stride (elements)
__global__ __launch_bounds__(256) void k_gemm3(
    const ushort* __restrict__ Eh, const ushort* __restrict__ El,
    const ushort* __restrict__ XTh, const ushort* __restrict__ XTl,
    const float* __restrict__ u_g, float* __restrict__ out) {
  __shared__ ushort As[128 * LSTR];
  __shared__ ushort Xs[128 * LSTR];
  __shared__ float ush[128];
  const int t = threadIdx.x;
  const int m0 = blockIdx.x * 128;
  const int c0 = blockIdx.y * 128;
  const int wid = t >> 6, lane = t & 63;
  const int wm = (wid & 1) * 64, wc = (wid >> 1) * 64;
  const int lm = lane & 15, q = lane >> 4;
  const int sr = t >> 1;        // staging row 0..127
  const int sc = (t & 1) * 32;  // staging k-offset: [sc, sc+32)
  if (t < 128) ush[t] = u_g[m0 + t];

  float4v acc[4][4];
#pragma unroll
  for (int i = 0; i < 4; ++i)
#pragma unroll
    for (int j = 0; j < 4; ++j) acc[i][j] = (float4v){0.f, 0.f, 0.f, 0.f};

  for (int seg = 0; seg < 3; ++seg) {
    const ushort* Ag = (seg == 1) ? El : Eh;
    const ushort* Xg = (seg == 2) ? XTl : XTh;
    for (int k0 = 0; k0 < 1024; k0 += 64) {
      __syncthreads();
      const ushort* ag = Ag + (size_t)(m0 + sr) * 1024 + k0 + sc;
      const ushort* xg = Xg + (size_t)(c0 + sr) * 1024 + k0 + sc;
      uint4 a0 = *(const uint4*)(ag);
      uint4 a1 = *(const uint4*)(ag + 8);
      uint4 a2 = *(const uint4*)(ag + 16);
      uint4 a3 = *(const uint4*)(ag + 24);
      uint4 x0 = *(const uint4*)(xg);
      uint4 x1 = *(const uint4*)(xg + 8);
      uint4 x2 = *(const uint4*)(xg + 16);
      uint4 x3 = *(const uint4*)(xg + 24);
      *(uint4*)&As[sr * LSTR + sc] = a0;
      *(uint4*)&As[sr * LSTR + sc + 8] = a1;
      *(uint4*)&As[sr * LSTR + sc + 16] = a2;
      *(uint4*)&As[sr * LSTR + sc + 24] = a3;
      *(uint4*)&Xs[sr * LSTR + sc] = x0;
      *(uint4*)&Xs[sr * LSTR + sc + 8] = x1;
      *(uint4*)&Xs[sr * LSTR + sc + 16] = x2;
      *(uint4*)&Xs[sr * LSTR + sc + 24] = x3;
      __syncthreads();
#pragma unroll
      for (int kk = 0; kk < 2; ++kk) {
        short8 af[4], xf[4];
#pragma unroll
        for (int i = 0; i < 4; ++i)
          af[i] = *(const short8*)&As[(wm + 16 * i + lm) * LSTR + kk * 32 +
                                      q * 8];
#pragma unroll
        for (int j = 0; j < 4; ++j)
          xf[j] = *(const short8*)&Xs[(wc + 16 * j + lm) * LSTR + kk * 32 +
                                      q * 8];
#pragma unroll
        for (int i = 0; i < 4; ++i)
#pragma unroll
          for (int j = 0; j < 4; ++j)
            acc[i][j] = __builtin_amdgcn_mfma_f32_16x16x32_bf16(
                af[i], xf[j], acc[i][j], 0, 0, 0);
      }
    }
  }
  // epilogue: D row = q*4 + reg, col = lm (m89-verified); scale by u_m
#pragma unroll
  for (int i = 0; i < 4; ++i) {
#pragma unroll
    for (int j = 0; j < 4; ++j) {
      const int ml = wm + 16 * i + q * 4;
      const int m = m0 + ml;
      const int c = c0 + wc + 16 * j + lm;
      const int bb = c >> 6, o = c & 63;
      float* dst = out + (size_t)bb * 65536 + (size_t)m * 64 + o;
#pragma unroll
      for (int r = 0; r < 4; ++r) dst[64 * r] = acc[i][j][r] * ush[ml + r];
    }
  }
}

// ---------------- kernel 3 (fp32 fallback): out = u ⊙ (E0·(v⊙XL)) ------------
__global__ __launch_bounds__(256) void k_gemm(const float* __restrict__ E0,
                                              const float* __restrict__ XL,
                                              const float* __restrict__ u_g,
                                              const float* __restrict__ v_g,
                                              float* __restrict__ out) {
  __shared__ float Asm[32][132];
  __shared__ float Xsm[32][132];
  const int t = threadIdx.x;
  const int m0 = blockIdx.x * 128;
  const int c0 = blockIdx.y * 128;
  const int my8 = (t >> 4) * 8;
  const int cx8 = (t & 15) * 8;
  const int kk = t & 31;
  const int rr = t >> 5;
  float acc[8][8] = {};

  for (int k0 = 0; k0 < 1024; k0 += 32) {
#pragma unroll
    for (int s = 0; s < 16; ++s)
      Asm[kk][rr + 8 * s] = E0[(size_t)(m0 + rr + 8 * s) * 1024 + k0 + kk];
#pragma unroll
    for (int s = 0; s < 4; ++s) {
      const int krow = k0 + rr + 8 * s;
      float vk = v_g[krow];
      float4 f = *(const float4*)&XL[(size_t)krow * 4096 + c0 + kk * 4];
      f.x *= vk;
      f.y *= vk;
      f.z *= vk;
      f.w *= vk;
      *(float4*)&Xsm[rr + 8 * s][kk * 4] = f;
    }
    __syncthreads();
#pragma unroll
    for (int k = 0; k < 32; ++k) {
      float a[8], xv[8];
      *(float4*)&a[0] = *(const float4*)&Asm[k][my8];
      *(float4*)&a[4] = *(const float4*)&Asm[k][my8 + 4];
      *(float4*)&xv[0] = *(const float4*)&Xsm[k][cx8];
      *(float4*)&xv[4] = *(const float4*)&Xsm[k][cx8 + 4];
#pragma unroll
      for (int i = 0; i < 8; ++i)
#pragma unroll
        for (int j = 0; j < 8; ++j) acc[i][j] += a[i] * xv[j];
    }
    __syncthreads();
  }

#pragma unroll
  for (int i = 0; i < 8; ++i) {
    const int m = m0 + my8 + i;
    const float um = u_g[m];
    const int c = c0 + cx8;
    const int bb = c >> 6, o = c & 63;
    float* dst = out + (size_t)bb * 65536 + (size_t)m * 64 + o;
#pragma unroll
    for (int j = 0; j < 8; ++j) dst[j] = acc[i][j] * um;
  }
}

// ---------------- launcher ---------------------------------------------------
extern "C" void kernel_launch(void* const* d_in, const int* in_sizes, int n_in,
                              void* d_out, int out_size, void* d_ws,
                              size_t ws_size, hipStream_t stream) {
  (void)in_sizes;
  (void)n_in;
  (void)out_size;
  const float* x = (const float*)d_in[0];
  const float* Alog = (const float*)d_in[1];
  const float* W1 = (const float*)d_in[2];
  const float* WV = (const float*)d_in[3];
  float* out = (float*)d_out;

  char* ws = (char*)d_ws;
  const size_t MB = 1024 * 1024;
  const size_t KB = 1024;
  const bool use_bf16 = ws_size >= (40 * MB + 256 * KB);
  const size_t P_BYTES = 20ull * NBAR * N_DIM * sizeof(float);  // 1.25 MB

  float* E0;
  float* XL;
  float* P;
  float* u_g;
  float* v_g;
  unsigned* ctrl;
  __hip_bfloat16 *Eh = nullptr, *El = nullptr, *XTh = nullptr, *XTl = nullptr;
  if (use_bf16) {
    P = (float*)(ws);                       // 1.25 MB (in dead E0 slot)
    E0 = (float*)(ws);                      // unused when write_bf16=1
    XL = (float*)(ws + 4 * MB);             // 16 MB
    Eh = (__hip_bfloat16*)(ws + 20 * MB);   // 2 MB
    El = (__hip_bfloat16*)(ws + 22 * MB);   // 2 MB
    XTh = (__hip_bfloat16*)(ws + 24 * MB);  // 8 MB
    XTl = (__hip_bfloat16*)(ws + 32 * MB);  // 8 MB -> 40 MB
    u_g = (float*)(ws + 40 * MB);                 // 4 KB
    v_g = (float*)(ws + 40 * MB + 4 * KB);        // 4 KB
    ctrl = (unsigned*)(ws + 40 * MB + 8 * KB);    // 4 KB (unused)
  } else {
    E0 = (float*)(ws);                      // 4 MB
    XL = (float*)(ws + 4 * MB);             // 16 MB
    P = (float*)(ws + 20 * MB);             // 1.25 MB
    u_g = (float*)(ws + 20 * MB + 1536 * KB);
    v_g = (float*)(ws + 20 * MB + 1540 * KB);
    ctrl = (unsigned*)(ws + 20 * MB + 1544 * KB);
  }

  hipMemsetAsync(P, 0, P_BYTES, stream);
  hipLaunchKernelGGL(k_front, dim3(256), dim3(1024), 0, stream, x, Alog, W1,
                     WV, E0, Eh, El, P, ctrl, u_g, v_g, XL, use_bf16 ? 1 : 0);
  if (use_bf16) {
    hipLaunchKernelGGL(k_xt, dim3(16, 64), dim3(256), 0, stream, XL, v_g, XTh,
                       XTl);
    hipLaunchKernelGGL(k_gemm3, dim3(8, 32), dim3(256), 0, stream,
                       (const ushort*)Eh, (const ushort*)El, (const ushort*)XTh,
                       (const ushort*)XTl, u_g, out);
  } else {
    hipLaunchKernelGGL(k_gemm, dim3(8, 32), dim3(256), 0, stream, E0, XL, u_g,
                       v_g, out);
  }
}

// Round 6
// 951.164 us; speedup vs baseline: 1.1180x; 1.1180x over previous
//
#include <hip/hip_runtime.h>
#include <hip/hip_bf16.h>

// KroneckerMixer: B=64, N=1024, K=64, BASIS=8, T=0.2, 20 sinkhorn iters.
// R12 pipeline (bf16 path, ws >= 40.25 MB):
//   k_front : fused, grid 256 x 1024, __launch_bounds__(1024, 4).
//     *** The (1024,4) launch bound is the round's fix: it raises the VGPR
//     cap from 64 (compiler default 8 waves/EU) to 128, which matches the
//     hard residency limit for 16-wave blocks (4 waves/SIMD). Without it,
//     e[] arrays in BOTH roles spill to scratch (R11: 196 MB scratch writes,
//     969 us). Occupancy is unchanged: 1 block/CU either way. ***
//     Blocks 0..15 = A-sinkhorn u/v solver (R9-verbatim): E in registers
//       (e[4][16], lane-stride-64 cols), flagless per-iteration exchange
//       buffers (value-as-flag, partials > 0), parallel retry gather.
//     Blocks 16..255 = W-path: one n per WAVE, fully in-register (R11 math,
//       harness-verified): lane c holds E[:,c] (e[64] VGPRs); row sums via
//       63-op ds_bpermute butterfly; u broadcast via per-wave 256B LDS line;
//       col pass lane-local; matmul in-wave with v folded after accum.
//       Distribution: blocks 16..79 take 5 n's, blocks 80..255 take 4
//       (64*5 + 176*4 = 1024), waves round-robin within the block.
//   k_xt    : transpose + v-scale + hi/lo split XL -> XTh/XTl bf16 [c][n].
//   k_gemm3 : out[m][c] = u_m*(Eh*XTh + El*XTh + Eh*XTl) via mfma 16x16x32.
// Fallback (small ws): fp32 k_gemm reading E0 with u/v folded.

#define N_DIM 1024
#define INV_T 5.0f
#define NBAR 16  // A-sinkhorn blocks

typedef __attribute__((ext_vector_type(8))) short short8;
typedef __attribute__((ext_vector_type(4))) float float4v;

// ---------------- wave64 sum reduction via DPP (VALU pipe) -------------------
// Result valid in lane 63.
__device__ __forceinline__ float wave_red_sum(float x) {
#define DPP_ADD(C)                                                            \
  {                                                                           \
    int _y = __builtin_amdgcn_update_dpp(0, __float_as_int(x), (C), 0xf, 0xf, \
                                         true);                               \
    x += __int_as_float(_y);                                                  \
  }
  DPP_ADD(0x111);
  DPP_ADD(0x112);
  DPP_ADD(0x114);
  DPP_ADD(0x118);
  DPP_ADD(0x142);
  DPP_ADD(0x143);
#undef DPP_ADD
  return x;
}

// ---------------- kernel 1: fused sinkA(u,v) + wpath -------------------------
// grid 256 x 1024.
__global__ __launch_bounds__(1024, 4) void k_front(
    const float* __restrict__ x, const float* __restrict__ L,
    const float* __restrict__ W1, const float* __restrict__ WV,
    float* __restrict__ E0, __hip_bfloat16* __restrict__ Eh,
    __hip_bfloat16* __restrict__ El, float* __restrict__ P,
    unsigned* __restrict__ ctrl, float* __restrict__ u_g,
    float* __restrict__ v_g, float* __restrict__ XL, int write_bf16) {
  __shared__ __align__(16) float smem[9312];
  const int t = threadIdx.x;
  const int bid = blockIdx.x;
  const int lane = t & 63;
  const int w = t >> 6;  // 0..15
  (void)ctrl;

  if (bid < NBAR) {
    // =================== A-sinkhorn u/v role (E in registers) ===============
    // Layout: e[j][k] = E[r0 + 4w + j][k*64 + lane]  (lane-stride-64 cols)
    float* v_s = smem;              // [1024]
    float* uS = smem + 1024;        // [64]
    float* red = smem + 1024 + 64;  // [8][1028] cross-wave reduce buffer
    const int b = bid;
    const int r0 = b * 64;

    // ---- prologue: e = exp(L/T); emit Eh/El (bf16 hi/lo) or E0 (fp32)
    float e[4][16];
#pragma unroll
    for (int j = 0; j < 4; ++j) {
      const int r = r0 + 4 * w + j;
      const float* Lr = L + (size_t)r * N_DIM + lane;
#pragma unroll
      for (int k = 0; k < 16; ++k) e[j][k] = __expf(Lr[k * 64] * INV_T);
      if (write_bf16) {
        __hip_bfloat16* EhR = Eh + (size_t)r * N_DIM + lane;
        __hip_bfloat16* ElR = El + (size_t)r * N_DIM + lane;
#pragma unroll
        for (int k = 0; k < 16; ++k) {
          __hip_bfloat16 h = __float2bfloat16(e[j][k]);
          EhR[k * 64] = h;
          ElR[k * 64] = __float2bfloat16(e[j][k] - __bfloat162float(h));
        }
      } else {
        float* ER = E0 + (size_t)r * N_DIM + lane;
#pragma unroll
        for (int k = 0; k < 16; ++k) ER[k * 64] = e[j][k];
      }
    }
    v_s[t] = 1.0f;  // iter0 row pass sums raw e (v == 1)
    __syncthreads();

    for (int it = 0; it < 20; ++it) {
      // ---- row pass: u_i = 1/sum_c e[i][c]*v[c]  (conflict-free v reads)
      float vv[16];
#pragma unroll
      for (int k = 0; k < 16; ++k) vv[k] = v_s[k * 64 + lane];
      float u[4];
#pragma unroll
      for (int j = 0; j < 4; ++j) {
        float p = 0.f;
#pragma unroll
        for (int k = 0; k < 16; ++k) p += e[j][k] * vv[k];
        p = wave_red_sum(p);  // lane 63
        u[j] = 1.0f /
               __int_as_float(__builtin_amdgcn_readlane(__float_as_int(p), 63));
      }
      // ---- col partials for this wave's 4 rows (col = k*64+lane)
      float cpl[16];
#pragma unroll
      for (int k = 0; k < 16; ++k)
        cpl[k] = e[0][k] * u[0] + e[1][k] * u[1] + e[2][k] * u[2] +
                 e[3][k] * u[3];
      // ---- cross-wave reduce 16->8 (all accesses lane-consecutive)
      if (w >= 8) {
#pragma unroll
        for (int k = 0; k < 16; ++k)
          red[(w - 8) * 1028 + k * 64 + lane] = cpl[k];
      }
      __syncthreads();
      if (w < 8) {
#pragma unroll
        for (int k = 0; k < 16; ++k) red[w * 1028 + k * 64 + lane] += cpl[k];
      }
      __syncthreads();
      // ---- block col sum (thread t = col t)
      float cp = 0.f;
#pragma unroll
      for (int ww = 0; ww < 8; ++ww) cp += red[ww * 1028 + t];
      // ---- exchange: store to THIS iteration's buffer (value-as-flag)
      float* Pit = P + (size_t)it * (NBAR * N_DIM);
      __hip_atomic_store(&Pit[b * N_DIM + t], cp, __ATOMIC_RELAXED,
                         __HIP_MEMORY_SCOPE_AGENT);
      if (it == 19 && lane == 0) {
#pragma unroll
        for (int j = 0; j < 4; ++j) uS[4 * w + j] = u[j];
      }
      // ---- gather: parallel loads, retry only zeros (partials are > 0)
      unsigned vals[NBAR];
#pragma unroll
      for (int pb = 0; pb < NBAR; ++pb)
        vals[pb] = (pb == b)
                       ? __float_as_uint(cp)
                       : __hip_atomic_load(
                             (const unsigned*)&Pit[pb * N_DIM + t],
                             __ATOMIC_RELAXED, __HIP_MEMORY_SCOPE_AGENT);
      for (;;) {
        unsigned miss = 0u;
#pragma unroll
        for (int pb = 0; pb < NBAR; ++pb) miss |= (vals[pb] == 0u) ? 1u : 0u;
        if (miss == 0u) break;
#pragma unroll
        for (int pb = 0; pb < NBAR; ++pb)
          if (vals[pb] == 0u)
            vals[pb] = __hip_atomic_load(
                (const unsigned*)&Pit[pb * N_DIM + t], __ATOMIC_RELAXED,
                __HIP_MEMORY_SCOPE_AGENT);
      }
      float s2 = 0.f;
#pragma unroll
      for (int pb = 0; pb < NBAR; ++pb) s2 += __uint_as_float(vals[pb]);
      v_s[t] = 1.0f / s2;
      __syncthreads();
    }
    // ---- epilogue: emit u (this block's 64 rows) and v (block 0)
    if (t < 64) u_g[r0 + t] = uS[t];
    if (b == 0) v_g[t] = v_s[t];
    return;  // A blocks do no W work
  }

  // =========== W-path: one n per wave, fully in-register ====================
  if (w >= 4) return;  // waves 0..3 only (one per SIMD); no barriers below
  float* ug = smem + w * 64;  // per-wave 256B u-broadcast line

  // blocks 16..79: 5 n's; blocks 80..255: 4 n's. 64*5 + 176*4 = 1024.
  const int idx = bid - NBAR;  // 0..239
  const int cnt = (idx < 64) ? 5 : 4;
  const int base_n = (idx < 64) ? idx * 5 : 320 + (idx - 64) * 4;

  const int pidx = lane << 2;  // bpermute byte index base

  for (int r = 0; r * 4 + w < cnt; ++r) {
    const int n = base_n + r * 4 + w;
    // ---- logits: lane c holds E[:,c]; e[i] = exp(INV_T * sum_k w1 WV[k][i][c])
    float w1[8];
#pragma unroll
    for (int k = 0; k < 8; ++k) w1[k] = W1[n * 8 + k];
    float e[64];
#pragma unroll
    for (int i = 0; i < 64; ++i) {
      float acc = 0.f;
#pragma unroll
      for (int k = 0; k < 8; ++k) acc += w1[k] * WV[k * 4096 + i * 64 + lane];
      e[i] = __expf(acc * INV_T);
    }

    // ---- 20 sinkhorn iterations, in-wave
    float v = 1.0f;
    for (int it = 0; it < 20; ++it) {
      // row sums via register butterfly reduce-transpose:
      // lane l ends with rowsum[l] = sum_c e_c[l]*v_c
      float a[32];
      {
        const bool hi = (lane & 32) != 0;
        const int pj = pidx ^ (32 << 2);
#pragma unroll
        for (int j = 0; j < 32; ++j) {
          float s0 = (hi ? e[j] : e[j + 32]) * v;
          float k0 = (hi ? e[j + 32] : e[j]) * v;
          a[j] = k0 + __int_as_float(__builtin_amdgcn_ds_bpermute(
                          pj, __float_as_int(s0)));
        }
      }
#define BSTAGE(D)                                                          \
  {                                                                        \
    const bool hi = (lane & (D)) != 0;                                     \
    const int pj = pidx ^ ((D) << 2);                                      \
    _Pragma("unroll") for (int j = 0; j < (D); ++j) {                      \
      float s0 = hi ? a[j] : a[j + (D)];                                   \
      float k0 = hi ? a[j + (D)] : a[j];                                   \
      a[j] = k0 + __int_as_float(                                          \
                      __builtin_amdgcn_ds_bpermute(pj, __float_as_int(s0))); \
    }                                                                      \
  }
      BSTAGE(16)
      BSTAGE(8)
      BSTAGE(4)
      BSTAGE(2)
      BSTAGE(1)
#undef BSTAGE
      const float u_l = 1.0f / a[0];
      ug[lane] = u_l;  // same-wave in-order DS pipe: reads below see this
      // col pass: v_c = 1/sum_i e[i][c]*u[i]  (u broadcast, v lane-local)
      float s2 = 0.f;
#pragma unroll
      for (int q = 0; q < 16; ++q) {
        float4 u4 = *(const float4*)&ug[4 * q];
        s2 += e[4 * q] * u4.x + e[4 * q + 1] * u4.y + e[4 * q + 2] * u4.z +
              e[4 * q + 3] * u4.w;
      }
      v = 1.0f / s2;
    }

    // ---- fold u into e:  e[i] <- e[i]*u[i]   (W[i][c] = e[i]*u[i]*v)
#pragma unroll
    for (int q = 0; q < 16; ++q) {
      float4 u4 = *(const float4*)&ug[4 * q];
      e[4 * q] *= u4.x;
      e[4 * q + 1] *= u4.y;
      e[4 * q + 2] *= u4.z;
      e[4 * q + 3] *= u4.w;
    }

    // ---- in-wave matmul: x_local[bb][c] = v * sum_i x[bb][n*64+i]*e[i]
    const float* xn = x + (size_t)n * 64;
    float* xl = XL + (size_t)n * 4096;
#pragma unroll 4
    for (int bb = 0; bb < 64; ++bb) {
      const float* xr = xn + (size_t)bb * 65536;
      float acc = 0.f;
#pragma unroll
      for (int q = 0; q < 16; ++q) {
        float4 xb = *(const float4*)&xr[4 * q];  // lane-uniform -> broadcast
        acc += xb.x * e[4 * q] + xb.y * e[4 * q + 1] + xb.z * e[4 * q + 2] +
               xb.w * e[4 * q + 3];
      }
      xl[bb * 64 + lane] = acc * v;  // coalesced 256B store
    }
  }
}

// ---------------- kernel 2b: transpose + v-scale + hi/lo split ---------------
// XTh/XTl[c][n] = hi/lo bf16 of (v[n] * XL[n][c]).
__global__ __launch_bounds__(256) void k_xt(const float* __restrict__ XL,
                                            const float* __restrict__ v_g,
                                            __hip_bfloat16* __restrict__ XTh,
                                            __hip_bfloat16* __restrict__ XTl) {
  __shared__ float T[64 * 68];
  __shared__ float vsh[64];
  const int t = threadIdx.x;
  const int n0 = blockIdx.x * 64;
  const int c0 = blockIdx.y * 64;
  if (t < 64) vsh[t] = v_g[n0 + t];
  {
    const int r = t >> 4;         // 0..15
    const int c4 = (t & 15) * 4;  // 0..60
#pragma unroll
    for (int p = 0; p < 4; ++p) {
      float4 f =
          *(const float4*)&XL[(size_t)(n0 + r + 16 * p) * 4096 + c0 + c4];
      *(float4*)&T[(r + 16 * p) * 68 + c4] = f;
    }
  }
  __syncthreads();
  const int cl = t >> 2;        // 0..63
  const int nb = (t & 3) * 16;  // 0,16,32,48
  __align__(16) __hip_bfloat16 hbuf[16];
  __align__(16) __hip_bfloat16 lbuf[16];
#pragma unroll
  for (int j = 0; j < 16; ++j) {
    float xv = T[(nb + j) * 68 + cl] * vsh[nb + j];
    __hip_bfloat16 h = __float2bfloat16(xv);
    hbuf[j] = h;
    lbuf[j] = __float2bfloat16(xv - __bfloat162float(h));
  }
  const size_t off = (size_t)(c0 + cl) * 1024 + n0 + nb;
  *(uint4*)&XTh[off] = *(uint4*)&hbuf[0];
  *(uint4*)&XTh[off + 8] = *(uint4*)&hbuf[8];
  *(uint4*)&XTl[off] = *(uint4*)&lbuf[0];
  *(uint4*)&XTl[off + 8] = *(uint4*)&lbuf[8];
}

// ---------------- kernel 3 (bf16): out = u ⊙ (Eh*XTh + El*XTh + Eh*XTl) ------
// D[m=1024][c=4096], 128x128 block tile, 4 waves each 64x64 of 16x16x32 MFMA.
#define LSTR 72  // padded LDS row stride (elements)
__global__ __launch_bounds__(256) void k_gemm3(
    const ushort* __restrict__ Eh, const ushort* __restrict__ El,
    const ushort* __restrict__ XTh, const ushort* __restrict__ XTl,
    const float* __restrict__ u_g, float* __restrict__ out) {
  __shared__ ushort As[128 * LSTR];
  __shared__ ushort Xs[128 * LSTR];
  __shared__ float ush[128];
  const int t = threadIdx.x;
  const int m0 = blockIdx.x * 128;
  const int c0 = blockIdx.y * 128;
  const int wid = t >> 6, lane = t & 63;
  const int wm = (wid & 1) * 64, wc = (wid >> 1) * 64;
  const int lm = lane & 15, q = lane >> 4;
  const int sr = t >> 1;        // staging row 0..127
  const int sc = (t & 1) * 32;  // staging k-offset: [sc, sc+32)
  if (t < 128) ush[t] = u_g[m0 + t];

  float4v acc[4][4];
#pragma unroll
  for (int i = 0; i < 4; ++i)
#pragma unroll
    for (int j = 0; j < 4; ++j) acc[i][j] = (float4v){0.f, 0.f, 0.f, 0.f};

  for (int seg = 0; seg < 3; ++seg) {
    const ushort* Ag = (seg == 1) ? El : Eh;
    const ushort* Xg = (seg == 2) ? XTl : XTh;
    for (int k0 = 0; k0 < 1024; k0 += 64) {
      __syncthreads();
      const ushort* ag = Ag + (size_t)(m0 + sr) * 1024 + k0 + sc;
      const ushort* xg = Xg + (size_t)(c0 + sr) * 1024 + k0 + sc;
      uint4 a0 = *(const uint4*)(ag);
      uint4 a1 = *(const uint4*)(ag + 8);
      uint4 a2 = *(const uint4*)(ag + 16);
      uint4 a3 = *(const uint4*)(ag + 24);
      uint4 x0 = *(const uint4*)(xg);
      uint4 x1 = *(const uint4*)(xg + 8);
      uint4 x2 = *(const uint4*)(xg + 16);
      uint4 x3 = *(const uint4*)(xg + 24);
      *(uint4*)&As[sr * LSTR + sc] = a0;
      *(uint4*)&As[sr * LSTR + sc + 8] = a1;
      *(uint4*)&As[sr * LSTR + sc + 16] = a2;
      *(uint4*)&As[sr * LSTR + sc + 24] = a3;
      *(uint4*)&Xs[sr * LSTR + sc] = x0;
      *(uint4*)&Xs[sr * LSTR + sc + 8] = x1;
      *(uint4*)&Xs[sr * LSTR + sc + 16] = x2;
      *(uint4*)&Xs[sr * LSTR + sc + 24] = x3;
      __syncthreads();
#pragma unroll
      for (int kk = 0; kk < 2; ++kk) {
        short8 af[4], xf[4];
#pragma unroll
        for (int i = 0; i < 4; ++i)
          af[i] = *(const short8*)&As[(wm + 16 * i + lm) * LSTR + kk * 32 +
                                      q * 8];
#pragma unroll
        for (int j = 0; j < 4; ++j)
          xf[j] = *(const short8*)&Xs[(wc + 16 * j + lm) * LSTR + kk * 32 +
                                      q * 8];
#pragma unroll
        for (int i = 0; i < 4; ++i)
#pragma unroll
          for (int j = 0; j < 4; ++j)
            acc[i][j] = __builtin_amdgcn_mfma_f32_16x16x32_bf16(
                af[i], xf[j], acc[i][j], 0, 0, 0);
      }
    }
  }
  // epilogue: D row = q*4 + reg, col = lm (m89-verified); scale by u_m
#pragma unroll
  for (int i = 0; i < 4; ++i) {
#pragma unroll
    for (int j = 0; j < 4; ++j) {
      const int ml = wm + 16 * i + q * 4;
      const int m = m0 + ml;
      const int c = c0 + wc + 16 * j + lm;
      const int bb = c >> 6, o = c & 63;
      float* dst = out + (size_t)bb * 65536 + (size_t)m * 64 + o;
#pragma unroll
      for (int r = 0; r < 4; ++r) dst[64 * r] = acc[i][j][r] * ush[ml + r];
    }
  }
}

// ---------------- kernel 3 (fp32 fallback): out = u ⊙ (E0·(v⊙XL)) ------------
__global__ __launch_bounds__(256) void k_gemm(const float* __restrict__ E0,
                                              const float* __restrict__ XL,
                                              const float* __restrict__ u_g,
                                              const float* __restrict__ v_g,
                                              float* __restrict__ out) {
  __shared__ float Asm[32][132];
  __shared__ float Xsm[32][132];
  const int t = threadIdx.x;
  const int m0 = blockIdx.x * 128;
  const int c0 = blockIdx.y * 128;
  const int my8 = (t >> 4) * 8;
  const int cx8 = (t & 15) * 8;
  const int kk = t & 31;
  const int rr = t >> 5;
  float acc[8][8] = {};

  for (int k0 = 0; k0 < 1024; k0 += 32) {
#pragma unroll
    for (int s = 0; s < 16; ++s)
      Asm[kk][rr + 8 * s] = E0[(size_t)(m0 + rr + 8 * s) * 1024 + k0 + kk];
#pragma unroll
    for (int s = 0; s < 4; ++s) {
      const int krow = k0 + rr + 8 * s;
      float vk = v_g[krow];
      float4 f = *(const float4*)&XL[(size_t)krow * 4096 + c0 + kk * 4];
      f.x *= vk;
      f.y *= vk;
      f.z *= vk;
      f.w *= vk;
      *(float4*)&Xsm[rr + 8 * s][kk * 4] = f;
    }
    __syncthreads();
#pragma unroll
    for (int k = 0; k < 32; ++k) {
      float a[8], xv[8];
      *(float4*)&a[0] = *(const float4*)&Asm[k][my8];
      *(float4*)&a[4] = *(const float4*)&Asm[k][my8 + 4];
      *(float4*)&xv[0] = *(const float4*)&Xsm[k][cx8];
      *(float4*)&xv[4] = *(const float4*)&Xsm[k][cx8 + 4];
#pragma unroll
      for (int i = 0; i < 8; ++i)
#pragma unroll
        for (int j = 0; j < 8; ++j) acc[i][j] += a[i] * xv[j];
    }
    __syncthreads();
  }

#pragma unroll
  for (int i = 0; i < 8; ++i) {
    const int m = m0 + my8 + i;
    const float um = u_g[m];
    const int c = c0 + cx8;
    const int bb = c >> 6, o = c & 63;
    float* dst = out + (size_t)bb * 65536 + (size_t)m * 64 + o;
#pragma unroll
    for (int j = 0; j < 8; ++j) dst[j] = acc[i][j] * um;
  }
}

// ---------------- launcher ---------------------------------------------------
extern "C" void kernel_launch(void* const* d_in, const int* in_sizes, int n_in,
                              void* d_out, int out_size, void* d_ws,
                              size_t ws_size, hipStream_t stream) {
  (void)in_sizes;
  (void)n_in;
  (void)out_size;
  const float* x = (const float*)d_in[0];
  const float* Alog = (const float*)d_in[1];
  const float* W1 = (const float*)d_in[2];
  const float* WV = (const float*)d_in[3];
  float* out = (float*)d_out;

  char* ws = (char*)d_ws;
  const size_t MB = 1024 * 1024;
  const size_t KB = 1024;
  const bool use_bf16 = ws_size >= (40 * MB + 256 * KB);
  const size_t P_BYTES = 20ull * NBAR * N_DIM * sizeof(float);  // 1.25 MB

  float* E0;
  float* XL;
  float* P;
  float* u_g;
  float* v_g;
  unsigned* ctrl;
  __hip_bfloat16 *Eh = nullptr, *El = nullptr, *XTh = nullptr, *XTl = nullptr;
  if (use_bf16) {
    P = (float*)(ws);                       // 1.25 MB (in dead E0 slot)
    E0 = (float*)(ws);                      // unused when write_bf16=1
    XL = (float*)(ws + 4 * MB);             // 16 MB
    Eh = (__hip_bfloat16*)(ws + 20 * MB);   // 2 MB
    El = (__hip_bfloat16*)(ws + 22 * MB);   // 2 MB
    XTh = (__hip_bfloat16*)(ws + 24 * MB);  // 8 MB
    XTl = (__hip_bfloat16*)(ws + 32 * MB);  // 8 MB -> 40 MB
    u_g = (float*)(ws + 40 * MB);                 // 4 KB
    v_g = (float*)(ws + 40 * MB + 4 * KB);        // 4 KB
    ctrl = (unsigned*)(ws + 40 * MB + 8 * KB);    // 4 KB (unused)
  } else {
    E0 = (float*)(ws);                      // 4 MB
    XL = (float*)(ws + 4 * MB);             // 16 MB
    P = (float*)(ws + 20 * MB);             // 1.25 MB
    u_g = (float*)(ws + 20 * MB + 1536 * KB);
    v_g = (float*)(ws + 20 * MB + 1540 * KB);
    ctrl = (unsigned*)(ws + 20 * MB + 1544 * KB);
  }

  hipMemsetAsync(P, 0, P_BYTES, stream);
  hipLaunchKernelGGL(k_front, dim3(256), dim3(1024), 0, stream, x, Alog, W1,
                     WV, E0, Eh, El, P, ctrl, u_g, v_g, XL, use_bf16 ? 1 : 0);
  if (use_bf16) {
    hipLaunchKernelGGL(k_xt, dim3(16, 64), dim3(256), 0, stream, XL, v_g, XTh,
                       XTl);
    hipLaunchKernelGGL(k_gemm3, dim3(8, 32), dim3(256), 0, stream,
                       (const ushort*)Eh, (const ushort*)El, (const ushort*)XTh,
                       (const ushort*)XTl, u_g, out);
  } else {
    hipLaunchKernelGGL(k_gemm, dim3(8, 32), dim3(256), 0, stream, E0, XL, u_g,
                       v_g, out);
  }
}

// Round 7
// 299.788 us; speedup vs baseline: 3.5473x; 3.1728x over previous
//
#include <hip/hip_runtime.h>
#include <hip/hip_bf16.h>

// KroneckerMixer: B=64, N=1024, K=64, BASIS=8, T=0.2, 20 sinkhorn iters.
// R13 pipeline (bf16 path, ws >= 40.25 MB):
//   k_front : fused, grid 288 x 256, __launch_bounds__(256, 2).
//     *** Spill fix: R11/R12 proved a 1024-thread block pins the VGPR cap at
//     64 (the launch_bounds 2nd arg behaved CUDA-style: 4 "blocks/CU" x 16
//     waves -> 8 waves/SIMD -> 64 regs; 196 MB scratch traffic, 951 us).
//     256-thread blocks with (256,2) give a 256-VGPR cap under EITHER
//     interpretation of the 2nd arg (2 waves/EU, or 2 blocks/CU = 2
//     waves/SIMD). All register arrays now fit: W ~140, A ~190 live. ***
//     Blocks 0..31  = A-sinkhorn u/v solver: 32 rows/block, thread holds
//       e[8][16] (lane-stride-64 cols). Per iter: 8 DPP row reduces -> u;
//       col partials -> 4-wave LDS reduce -> per-block partial store (sc1,
//       value-as-flag, per-iteration buffers, partials > 0); gather = 4
//       col-chunks x 32 parallel loads, retry only zeros. 20 buffers =
//       2.5 MB, pre-zeroed. No flags, no grid barrier, skew-tolerant.
//     Blocks 32..287 = W-path (R11 math, verified): one n per WAVE, fully
//       in-register: lane c holds E[:,c] (e[64]); 63-op ds_bpermute
//       butterfly row sums; u via per-wave 256B LDS line; col pass
//       lane-local; in-wave matmul with v folded after accumulation.
//       n = (bid-32)*4 + w  -> exactly 1024 n's.
//     288 blocks at >=2 blocks/CU capacity: all co-resident regardless of
//     dispatch order -> A spin-exchange is safe.
//   k_xt    : transpose + v-scale + hi/lo split XL -> XTh/XTl bf16 [c][n].
//   k_gemm3 : out[m][c] = u_m*(Eh*XTh + El*XTh + Eh*XTl) via mfma 16x16x32.
// Fallback (small ws): fp32 k_gemm reading E0 with u/v folded.

#define N_DIM 1024
#define INV_T 5.0f
#define ABLK 32  // A-sinkhorn blocks (32 rows each)

typedef __attribute__((ext_vector_type(8))) short short8;
typedef __attribute__((ext_vector_type(4))) float float4v;

// ---------------- wave64 sum reduction via DPP (VALU pipe) -------------------
// Result valid in lane 63.
__device__ __forceinline__ float wave_red_sum(float x) {
#define DPP_ADD(C)                                                            \
  {                                                                           \
    int _y = __builtin_amdgcn_update_dpp(0, __float_as_int(x), (C), 0xf, 0xf, \
                                         true);                               \
    x += __int_as_float(_y);                                                  \
  }
  DPP_ADD(0x111);
  DPP_ADD(0x112);
  DPP_ADD(0x114);
  DPP_ADD(0x118);
  DPP_ADD(0x142);
  DPP_ADD(0x143);
#undef DPP_ADD
  return x;
}

// ---------------- kernel 1: fused sinkA(u,v) + wpath -------------------------
// grid 288 x 256.
__global__ __launch_bounds__(256, 2) void k_front(
    const float* __restrict__ x, const float* __restrict__ L,
    const float* __restrict__ W1, const float* __restrict__ WV,
    float* __restrict__ E0, __hip_bfloat16* __restrict__ Eh,
    __hip_bfloat16* __restrict__ El, float* __restrict__ P,
    unsigned* __restrict__ ctrl, float* __restrict__ u_g,
    float* __restrict__ v_g, float* __restrict__ XL, int write_bf16) {
  __shared__ __align__(16) float smem[5136];
  const int t = threadIdx.x;  // 0..255
  const int bid = blockIdx.x;
  const int lane = t & 63;
  const int w = t >> 6;  // 0..3
  (void)ctrl;

  if (bid < ABLK) {
    // =================== A-sinkhorn u/v role (E in registers) ===============
    // Thread layout: e[j][k] = E[r0 + 8w + j][k*64 + lane], j<8, k<16.
    float* v_s = smem;          // [1024]
    float* red = smem + 1024;   // [4][1028] cross-wave col reduce
    const int b = bid;
    const int r0 = b * 32;

    // ---- prologue: e = exp(L/T); emit Eh/El (bf16 hi/lo) or E0 (fp32)
    float e[8][16];
#pragma unroll
    for (int j = 0; j < 8; ++j) {
      const int r = r0 + 8 * w + j;
      const float* Lr = L + (size_t)r * N_DIM + lane;
#pragma unroll
      for (int k = 0; k < 16; ++k) e[j][k] = __expf(Lr[k * 64] * INV_T);
      if (write_bf16) {
        __hip_bfloat16* EhR = Eh + (size_t)r * N_DIM + lane;
        __hip_bfloat16* ElR = El + (size_t)r * N_DIM + lane;
#pragma unroll
        for (int k = 0; k < 16; ++k) {
          __hip_bfloat16 h = __float2bfloat16(e[j][k]);
          EhR[k * 64] = h;
          ElR[k * 64] = __float2bfloat16(e[j][k] - __bfloat162float(h));
        }
      } else {
        float* ER = E0 + (size_t)r * N_DIM + lane;
#pragma unroll
        for (int k = 0; k < 16; ++k) ER[k * 64] = e[j][k];
      }
    }
    // v == 1 for iter 0
    v_s[t] = 1.0f;
    v_s[t + 256] = 1.0f;
    v_s[t + 512] = 1.0f;
    v_s[t + 768] = 1.0f;
    __syncthreads();

    for (int it = 0; it < 20; ++it) {
      // ---- row pass: u_i = 1/sum_c e[i][c]*v[c]
      float vv[16];
#pragma unroll
      for (int k = 0; k < 16; ++k) vv[k] = v_s[k * 64 + lane];
      float u[8];
#pragma unroll
      for (int j = 0; j < 8; ++j) {
        float p = 0.f;
#pragma unroll
        for (int k = 0; k < 16; ++k) p += e[j][k] * vv[k];
        p = wave_red_sum(p);  // lane 63
        u[j] = 1.0f /
               __int_as_float(__builtin_amdgcn_readlane(__float_as_int(p), 63));
      }
      // ---- col partials for this wave's 8 rows (col = k*64+lane)
#pragma unroll
      for (int k = 0; k < 16; ++k) {
        float cpl = e[0][k] * u[0] + e[1][k] * u[1] + e[2][k] * u[2] +
                    e[3][k] * u[3] + e[4][k] * u[4] + e[5][k] * u[5] +
                    e[6][k] * u[6] + e[7][k] * u[7];
        red[w * 1028 + k * 64 + lane] = cpl;
      }
      if (it == 19 && lane == 0) {
#pragma unroll
        for (int j = 0; j < 8; ++j) u_g[r0 + 8 * w + j] = u[j];
      }
      __syncthreads();
      // ---- block col sums (thread t -> cols t, t+256, t+512, t+768) + post
      float* Pit = P + (size_t)it * (ABLK * N_DIM);
      float cp4[4];
#pragma unroll
      for (int cc = 0; cc < 4; ++cc) {
        const int c = t + cc * 256;
        cp4[cc] = red[c] + red[1028 + c] + red[2 * 1028 + c] + red[3 * 1028 + c];
        __hip_atomic_store(&Pit[b * N_DIM + c], cp4[cc], __ATOMIC_RELAXED,
                           __HIP_MEMORY_SCOPE_AGENT);
      }
      // ---- gather per chunk: 32 parallel loads, retry only zeros (> 0 data)
      for (int cc = 0; cc < 4; ++cc) {
        const int c = t + cc * 256;
        unsigned vals[ABLK];
#pragma unroll
        for (int pb = 0; pb < ABLK; ++pb)
          vals[pb] =
              __hip_atomic_load((const unsigned*)&Pit[pb * N_DIM + c],
                                __ATOMIC_RELAXED, __HIP_MEMORY_SCOPE_AGENT);
        for (;;) {
          unsigned miss = 0u;
#pragma unroll
          for (int pb = 0; pb < ABLK; ++pb) miss |= (vals[pb] == 0u) ? 1u : 0u;
          if (miss == 0u) break;
#pragma unroll
          for (int pb = 0; pb < ABLK; ++pb)
            if (vals[pb] == 0u)
              vals[pb] = __hip_atomic_load(
                  (const unsigned*)&Pit[pb * N_DIM + c], __ATOMIC_RELAXED,
                  __HIP_MEMORY_SCOPE_AGENT);
        }
        float s2 = 0.f;
#pragma unroll
        for (int pb = 0; pb < ABLK; ++pb) s2 += __uint_as_float(vals[pb]);
        v_s[c] = 1.0f / s2;
      }
      __syncthreads();
    }
    // ---- epilogue: v from block 0 (u already written at it==19)
    if (b == 0) {
#pragma unroll
      for (int cc = 0; cc < 4; ++cc) v_g[t + cc * 256] = v_s[t + cc * 256];
    }
    return;
  }

  // =========== W-path: one n per wave, fully in-register ====================
  float* ug = smem + w * 64;  // per-wave 256B u-broadcast line
  const int n = (bid - ABLK) * 4 + w;  // 0..1023 exactly

  const int pidx = lane << 2;  // bpermute byte index base

  // ---- logits: lane c holds E[:,c]; e[i] = exp(INV_T * sum_k w1 WV[k][i][c])
  float w1[8];
#pragma unroll
  for (int k = 0; k < 8; ++k) w1[k] = W1[n * 8 + k];
  float e[64];
#pragma unroll
  for (int i = 0; i < 64; ++i) {
    float acc = 0.f;
#pragma unroll
    for (int k = 0; k < 8; ++k) acc += w1[k] * WV[k * 4096 + i * 64 + lane];
    e[i] = __expf(acc * INV_T);
  }

  // ---- 20 sinkhorn iterations, in-wave
  float v = 1.0f;
  for (int it = 0; it < 20; ++it) {
    // row sums via register butterfly reduce-transpose:
    // lane l ends with rowsum[l] = sum_c e_c[l]*v_c
    float a[32];
    {
      const bool hi = (lane & 32) != 0;
      const int pj = pidx ^ (32 << 2);
#pragma unroll
      for (int j = 0; j < 32; ++j) {
        float s0 = (hi ? e[j] : e[j + 32]) * v;
        float k0 = (hi ? e[j + 32] : e[j]) * v;
        a[j] = k0 + __int_as_float(__builtin_amdgcn_ds_bpermute(
                        pj, __float_as_int(s0)));
      }
    }
#define BSTAGE(D)                                                          \
  {                                                                        \
    const bool hi = (lane & (D)) != 0;                                     \
    const int pj = pidx ^ ((D) << 2);                                      \
    _Pragma("unroll") for (int j = 0; j < (D); ++j) {                      \
      float s0 = hi ? a[j] : a[j + (D)];                                   \
      float k0 = hi ? a[j + (D)] : a[j];                                   \
      a[j] = k0 + __int_as_float(                                          \
                      __builtin_amdgcn_ds_bpermute(pj, __float_as_int(s0))); \
    }                                                                      \
  }
    BSTAGE(16)
    BSTAGE(8)
    BSTAGE(4)
    BSTAGE(2)
    BSTAGE(1)
#undef BSTAGE
    const float u_l = 1.0f / a[0];
    ug[lane] = u_l;  // same-wave in-order DS pipe: reads below see this
    // col pass: v_c = 1/sum_i e[i][c]*u[i]  (u broadcast, v lane-local)
    float s2 = 0.f;
#pragma unroll
    for (int q = 0; q < 16; ++q) {
      float4 u4 = *(const float4*)&ug[4 * q];
      s2 += e[4 * q] * u4.x + e[4 * q + 1] * u4.y + e[4 * q + 2] * u4.z +
            e[4 * q + 3] * u4.w;
    }
    v = 1.0f / s2;
  }

  // ---- fold u into e:  e[i] <- e[i]*u[i]   (W[i][c] = e[i]*u[i]*v)
#pragma unroll
  for (int q = 0; q < 16; ++q) {
    float4 u4 = *(const float4*)&ug[4 * q];
    e[4 * q] *= u4.x;
    e[4 * q + 1] *= u4.y;
    e[4 * q + 2] *= u4.z;
    e[4 * q + 3] *= u4.w;
  }

  // ---- in-wave matmul: x_local[bb][c] = v * sum_i x[bb][n*64+i]*e[i]
  const float* xn = x + (size_t)n * 64;
  float* xl = XL + (size_t)n * 4096;
#pragma unroll 4
  for (int bb = 0; bb < 64; ++bb) {
    const float* xr = xn + (size_t)bb * 65536;
    float acc = 0.f;
#pragma unroll
    for (int q = 0; q < 16; ++q) {
      float4 xb = *(const float4*)&xr[4 * q];  // lane-uniform -> broadcast
      acc += xb.x * e[4 * q] + xb.y * e[4 * q + 1] + xb.z * e[4 * q + 2] +
             xb.w * e[4 * q + 3];
    }
    xl[bb * 64 + lane] = acc * v;  // coalesced 256B store
  }
}

// ---------------- kernel 2b: transpose + v-scale + hi/lo split ---------------
// XTh/XTl[c][n] = hi/lo bf16 of (v[n] * XL[n][c]).
__global__ __launch_bounds__(256) void k_xt(const float* __restrict__ XL,
                                            const float* __restrict__ v_g,
                                            __hip_bfloat16* __restrict__ XTh,
                                            __hip_bfloat16* __restrict__ XTl) {
  __shared__ float T[64 * 68];
  __shared__ float vsh[64];
  const int t = threadIdx.x;
  const int n0 = blockIdx.x * 64;
  const int c0 = blockIdx.y * 64;
  if (t < 64) vsh[t] = v_g[n0 + t];
  {
    const int r = t >> 4;         // 0..15
    const int c4 = (t & 15) * 4;  // 0..60
#pragma unroll
    for (int p = 0; p < 4; ++p) {
      float4 f =
          *(const float4*)&XL[(size_t)(n0 + r + 16 * p) * 4096 + c0 + c4];
      *(float4*)&T[(r + 16 * p) * 68 + c4] = f;
    }
  }
  __syncthreads();
  const int cl = t >> 2;        // 0..63
  const int nb = (t & 3) * 16;  // 0,16,32,48
  __align__(16) __hip_bfloat16 hbuf[16];
  __align__(16) __hip_bfloat16 lbuf[16];
#pragma unroll
  for (int j = 0; j < 16; ++j) {
    float xv = T[(nb + j) * 68 + cl] * vsh[nb + j];
    __hip_bfloat16 h = __float2bfloat16(xv);
    hbuf[j] = h;
    lbuf[j] = __float2bfloat16(xv - __bfloat162float(h));
  }
  const size_t off = (size_t)(c0 + cl) * 1024 + n0 + nb;
  *(uint4*)&XTh[off] = *(uint4*)&hbuf[0];
  *(uint4*)&XTh[off + 8] = *(uint4*)&hbuf[8];
  *(uint4*)&XTl[off] = *(uint4*)&lbuf[0];
  *(uint4*)&XTl[off + 8] = *(uint4*)&lbuf[8];
}

// ---------------- kernel 3 (bf16): out = u ⊙ (Eh*XTh + El*XTh + Eh*XTl) ------
// D[m=1024][c=4096], 128x128 block tile, 4 waves each 64x64 of 16x16x32 MFMA.
#define LSTR 72  // padded LDS row stride (elements)
__global__ __launch_bounds__(256) void k_gemm3(
    const ushort* __restrict__ Eh, const ushort* __restrict__ El,
    const ushort* __restrict__ XTh, const ushort* __restrict__ XTl,
    const float* __restrict__ u_g, float* __restrict__ out) {
  __shared__ ushort As[128 * LSTR];
  __shared__ ushort Xs[128 * LSTR];
  __shared__ float ush[128];
  const int t = threadIdx.x;
  const int m0 = blockIdx.x * 128;
  const int c0 = blockIdx.y * 128;
  const int wid = t >> 6, lane = t & 63;
  const int wm = (wid & 1) * 64, wc = (wid >> 1) * 64;
  const int lm = lane & 15, q = lane >> 4;
  const int sr = t >> 1;        // staging row 0..127
  const int sc = (t & 1) * 32;  // staging k-offset: [sc, sc+32)
  if (t < 128) ush[t] = u_g[m0 + t];

  float4v acc[4][4];
#pragma unroll
  for (int i = 0; i < 4; ++i)
#pragma unroll
    for (int j = 0; j < 4; ++j) acc[i][j] = (float4v){0.f, 0.f, 0.f, 0.f};

  for (int seg = 0; seg < 3; ++seg) {
    const ushort* Ag = (seg == 1) ? El : Eh;
    const ushort* Xg = (seg == 2) ? XTl : XTh;
    for (int k0 = 0; k0 < 1024; k0 += 64) {
      __syncthreads();
      const ushort* ag = Ag + (size_t)(m0 + sr) * 1024 + k0 + sc;
      const ushort* xg = Xg + (size_t)(c0 + sr) * 1024 + k0 + sc;
      uint4 a0 = *(const uint4*)(ag);
      uint4 a1 = *(const uint4*)(ag + 8);
      uint4 a2 = *(const uint4*)(ag + 16);
      uint4 a3 = *(const uint4*)(ag + 24);
      uint4 x0 = *(const uint4*)(xg);
      uint4 x1 = *(const uint4*)(xg + 8);
      uint4 x2 = *(const uint4*)(xg + 16);
      uint4 x3 = *(const uint4*)(xg + 24);
      *(uint4*)&As[sr * LSTR + sc] = a0;
      *(uint4*)&As[sr * LSTR + sc + 8] = a1;
      *(uint4*)&As[sr * LSTR + sc + 16] = a2;
      *(uint4*)&As[sr * LSTR + sc + 24] = a3;
      *(uint4*)&Xs[sr * LSTR + sc] = x0;
      *(uint4*)&Xs[sr * LSTR + sc + 8] = x1;
      *(uint4*)&Xs[sr * LSTR + sc + 16] = x2;
      *(uint4*)&Xs[sr * LSTR + sc + 24] = x3;
      __syncthreads();
#pragma unroll
      for (int kk = 0; kk < 2; ++kk) {
        short8 af[4], xf[4];
#pragma unroll
        for (int i = 0; i < 4; ++i)
          af[i] = *(const short8*)&As[(wm + 16 * i + lm) * LSTR + kk * 32 +
                                      q * 8];
#pragma unroll
        for (int j = 0; j < 4; ++j)
          xf[j] = *(const short8*)&Xs[(wc + 16 * j + lm) * LSTR + kk * 32 +
                                      q * 8];
#pragma unroll
        for (int i = 0; i < 4; ++i)
#pragma unroll
          for (int j = 0; j < 4; ++j)
            acc[i][j] = __builtin_amdgcn_mfma_f32_16x16x32_bf16(
                af[i], xf[j], acc[i][j], 0, 0, 0);
      }
    }
  }
  // epilogue: D row = q*4 + reg, col = lm (m89-verified); scale by u_m
#pragma unroll
  for (int i = 0; i < 4; ++i) {
#pragma unroll
    for (int j = 0; j < 4; ++j) {
      const int ml = wm + 16 * i + q * 4;
      const int m = m0 + ml;
      const int c = c0 + wc + 16 * j + lm;
      const int bb = c >> 6, o = c & 63;
      float* dst = out + (size_t)bb * 65536 + (size_t)m * 64 + o;
#pragma unroll
      for (int r = 0; r < 4; ++r) dst[64 * r] = acc[i][j][r] * ush[ml + r];
    }
  }
}

// ---------------- kernel 3 (fp32 fallback): out = u ⊙ (E0·(v⊙XL)) ------------
__global__ __launch_bounds__(256) void k_gemm(const float* __restrict__ E0,
                                              const float* __restrict__ XL,
                                              const float* __restrict__ u_g,
                                              const float* __restrict__ v_g,
                                              float* __restrict__ out) {
  __shared__ float Asm[32][132];
  __shared__ float Xsm[32][132];
  const int t = threadIdx.x;
  const int m0 = blockIdx.x * 128;
  const int c0 = blockIdx.y * 128;
  const int my8 = (t >> 4) * 8;
  const int cx8 = (t & 15) * 8;
  const int kk = t & 31;
  const int rr = t >> 5;
  float acc[8][8] = {};

  for (int k0 = 0; k0 < 1024; k0 += 32) {
#pragma unroll
    for (int s = 0; s < 16; ++s)
      Asm[kk][rr + 8 * s] = E0[(size_t)(m0 + rr + 8 * s) * 1024 + k0 + kk];
#pragma unroll
    for (int s = 0; s < 4; ++s) {
      const int krow = k0 + rr + 8 * s;
      float vk = v_g[krow];
      float4 f = *(const float4*)&XL[(size_t)krow * 4096 + c0 + kk * 4];
      f.x *= vk;
      f.y *= vk;
      f.z *= vk;
      f.w *= vk;
      *(float4*)&Xsm[rr + 8 * s][kk * 4] = f;
    }
    __syncthreads();
#pragma unroll
    for (int k = 0; k < 32; ++k) {
      float a[8], xv[8];
      *(float4*)&a[0] = *(const float4*)&Asm[k][my8];
      *(float4*)&a[4] = *(const float4*)&Asm[k][my8 + 4];
      *(float4*)&xv[0] = *(const float4*)&Xsm[k][cx8];
      *(float4*)&xv[4] = *(const float4*)&Xsm[k][cx8 + 4];
#pragma unroll
      for (int i = 0; i < 8; ++i)
#pragma unroll
        for (int j = 0; j < 8; ++j) acc[i][j] += a[i] * xv[j];
    }
    __syncthreads();
  }

#pragma unroll
  for (int i = 0; i < 8; ++i) {
    const int m = m0 + my8 + i;
    const float um = u_g[m];
    const int c = c0 + cx8;
    const int bb = c >> 6, o = c & 63;
    float* dst = out + (size_t)bb * 65536 + (size_t)m * 64 + o;
#pragma unroll
    for (int j = 0; j < 8; ++j) dst[j] = acc[i][j] * um;
  }
}

// ---------------- launcher ---------------------------------------------------
extern "C" void kernel_launch(void* const* d_in, const int* in_sizes, int n_in,
                              void* d_out, int out_size, void* d_ws,
                              size_t ws_size, hipStream_t stream) {
  (void)in_sizes;
  (void)n_in;
  (void)out_size;
  const float* x = (const float*)d_in[0];
  const float* Alog = (const float*)d_in[1];
  const float* W1 = (const float*)d_in[2];
  const float* WV = (const float*)d_in[3];
  float* out = (float*)d_out;

  char* ws = (char*)d_ws;
  const size_t MB = 1024 * 1024;
  const size_t KB = 1024;
  const bool use_bf16 = ws_size >= (40 * MB + 256 * KB);
  const size_t P_BYTES = 20ull * ABLK * N_DIM * sizeof(float);  // 2.5 MB

  float* E0;
  float* XL;
  float* P;
  float* u_g;
  float* v_g;
  unsigned* ctrl;
  __hip_bfloat16 *Eh = nullptr, *El = nullptr, *XTh = nullptr, *XTl = nullptr;
  if (use_bf16) {
    P = (float*)(ws);                       // 2.5 MB (in dead E0 slot, 4 MB)
    E0 = (float*)(ws);                      // unused when write_bf16=1
    XL = (float*)(ws + 4 * MB);             // 16 MB
    Eh = (__hip_bfloat16*)(ws + 20 * MB);   // 2 MB
    El = (__hip_bfloat16*)(ws + 22 * MB);   // 2 MB
    XTh = (__hip_bfloat16*)(ws + 24 * MB);  // 8 MB
    XTl = (__hip_bfloat16*)(ws + 32 * MB);  // 8 MB -> 40 MB
    u_g = (float*)(ws + 40 * MB);                 // 4 KB
    v_g = (float*)(ws + 40 * MB + 4 * KB);        // 4 KB
    ctrl = (unsigned*)(ws + 40 * MB + 8 * KB);    // 4 KB (unused)
  } else {
    E0 = (float*)(ws);                      // 4 MB
    XL = (float*)(ws + 4 * MB);             // 16 MB
    P = (float*)(ws + 20 * MB);             // 2.5 MB
    u_g = (float*)(ws + 20 * MB + 2560 * KB);
    v_g = (float*)(ws + 20 * MB + 2564 * KB);
    ctrl = (unsigned*)(ws + 20 * MB + 2568 * KB);
  }

  hipMemsetAsync(P, 0, P_BYTES, stream);
  hipLaunchKernelGGL(k_front, dim3(ABLK + 256), dim3(256), 0, stream, x, Alog,
                     W1, WV, E0, Eh, El, P, ctrl, u_g, v_g, XL,
                     use_bf16 ? 1 : 0);
  if (use_bf16) {
    hipLaunchKernelGGL(k_xt, dim3(16, 64), dim3(256), 0, stream, XL, v_g, XTh,
                       XTl);
    hipLaunchKernelGGL(k_gemm3, dim3(8, 32), dim3(256), 0, stream,
                       (const ushort*)Eh, (const ushort*)El, (const ushort*)XTh,
                       (const ushort*)XTl, u_g, out);
  } else {
    hipLaunchKernelGGL(k_gemm, dim3(8, 32), dim3(256), 0, stream, E0, XL, u_g,
                       v_g, out);
  }
}